// Round 15
// baseline (245.710 us; speedup 1.0000x reference)
//
#include <hip/hip_runtime.h>
#include <hip/hip_fp16.h>
#include <math.h>

#define BB 32768
#define EE 16
#define HH 128
#define KP 160          // padded K: 16 x + 128 h + 16 zeros
#define XS 168          // xh row stride (f16 elems): 168*2B=336B -> 16B-aligned, 8 bank-start spread
#define OBS 8
#define NSTEP 19
#define TPB 1024
#define MROWS 64        // batch rows per block (128 spills: R5/R13 -- twice-dead)
#define KT 5            // K-tiles of 32
#define XBUF (MROWS * XS)   // one xh buffer (f16 elems); two buffers double-buffered

typedef short s16x8 __attribute__((ext_vector_type(8)));     // raw 16-bit x8 (LDS storage view)
typedef _Float16 h16x8 __attribute__((ext_vector_type(8)));  // 8 fp16 (4 VGPRs), MFMA A/B frag
typedef float f32x4 __attribute__((ext_vector_type(4)));     // MFMA C/D frag

// Transcendentals via the NATIVE v_exp_f32 (2^x) -- bypasses any libm range-reduction
// __expf might carry.  exp(-x) = exp2(-log2e*x); constants pre-folded.
#define NLOG2E  1.4426950408889634f
#define N2LOG2E 2.8853900817779268f
__device__ __forceinline__ float sigm(float x){
    return __builtin_amdgcn_rcpf(1.0f + __builtin_amdgcn_exp2f(-NLOG2E * x));
}
__device__ __forceinline__ float ftanh(float x){
    float e = __builtin_amdgcn_exp2f(-N2LOG2E * x);
    return (1.f - e) * __builtin_amdgcn_rcpf(1.f + e);
}
__device__ __forceinline__ unsigned short f2h(float x){
    __half h = __float2half(x);                 // RNE, single v_cvt_f16_f32
    return __half_as_ushort(h);
}
__device__ __forceinline__ float h2f(unsigned short u){ return __half2float(__ushort_as_half(u)); }

// Pack W_cat = [W_ih | W_hh] (K=144, zero-pad to 160) into MFMA A-operand fragment order,
// single fp16.  Frag (JT 0..31, kt 0..4): lane l, elem j holds
//   W_cat[k = kt*32 + (l>>4)*8 + j][jg = JT*16 + (l&15)],  jg = 4*j_hidden + gate.
__global__ __launch_bounds__(256) void k_prep(
    const float* __restrict__ W_ih, const float* __restrict__ W_hh,
    unsigned short* __restrict__ Whi)
{
    int idx = blockIdx.x * 256 + threadIdx.x;      // exactly 32*5*64*8 = 81920 threads
    int j    = idx & 7;
    int lane = (idx >> 3) & 63;
    int kt   = (idx >> 9) % KT;
    int JT   = idx / (KT * 512);
    int k  = kt * 32 + ((lane >> 4) << 3) + j;
    int jg = JT * 16 + (lane & 15);
    int col = (jg & 3) * HH + (jg >> 2);           // original gate row: g*128 + j_hidden
    float wv = 0.f;
    if (k < EE)            wv = W_ih[col * EE + k];
    else if (k < EE + HH)  wv = W_hh[col * HH + (k - EE)];
    Whi[idx] = f2h(wv);
}

// R14 base (196us kernel) + three latency/VALU cuts, all value-preserving:
//  1. sigm/ftanh via __builtin_amdgcn_exp2f (native v_exp_f32) -- if __expf was lowering
//     to a libm range-reduced sequence this removes the dominant hidden VALU cost.
//  2. Loop-invariant readout operands (wout 4xfloat4, wemb/bemb scalars) hoisted to regs.
//  3. obs frames staged to LDS once (64 rows x 9 x 2 f32 = 4.6KB); all per-step global
//     obs loads (uncoalesced 4B VMEM, unhoistable across `#pragma unroll 1` steps)
//     become ds_reads of the same values; identical subtractions -> same deltas.
__global__ __attribute__((amdgpu_flat_work_group_size(TPB, TPB)))
           __attribute__((amdgpu_waves_per_eu(4, 4)))
void k_lstm(
    const float* __restrict__ obs,
    const float* __restrict__ W_emb, const float* __restrict__ b_emb,
    const float* __restrict__ b_ih,  const float* __restrict__ b_hh,
    const unsigned short* __restrict__ Whi,
    const float* __restrict__ W_out, const float* __restrict__ b_out,
    float* __restrict__ out)
{
    __shared__ unsigned short xhh[2 * XBUF];     // fp16 of [x(16)|h(128)|0(16)|pad] x2 buffers
    __shared__ float wout[2 * HH];
    __shared__ float wemb[EE * 2];
    __shared__ float bemb[EE];
    __shared__ float obs_l[MROWS * 20];          // [row][frame 0..8][xy], stride 20 f32

    const int t    = threadIdx.x;
    const int lane = t & 63;
    const int w    = t >> 6;                     // wave 0..15: gate-cols jg in [w*32,(w+1)*32)
    const int row0 = blockIdx.x * MROWS;

    if (t < 2 * HH) wout[t] = W_out[t];          // rows 0,1 of W_out (contiguous)
    if (t < EE * 2) wemb[t] = W_emb[t];
    if (t < EE)     bemb[t] = b_emb[t];
    for (int i = t; i < 2 * XBUF; i += TPB) { xhh[i] = 0; }
    for (int i = t; i < MROWS * 18; i += TPB) {  // stage obs frames for this block's rows
        int row = i / 18, rem = i % 18, si = rem >> 1, xy = rem & 1;
        obs_l[row * 20 + (si << 1) + xy] = obs[(size_t)si * BB * 2 + (row0 + row) * 2 + xy];
    }

    // per-lane gate biases: acc[mt] reg r <-> jg = (2w+mt)*16 + (lane>>4)*4 + r
    f32x4 bias[2];
#pragma unroll
    for (int mt = 0; mt < 2; mt++)
#pragma unroll
        for (int r = 0; r < 4; r++) {
            int jg  = (2 * w + mt) * 16 + ((lane >> 4) << 2) + r;
            int col = (jg & 3) * HH + (jg >> 2);
            bias[mt][r] = b_ih[col] + b_hh[col];
        }
    const float bo0 = b_out[0], bo1 = b_out[1];

    // A-fragments: loop-invariant across all steps -> load ONCE into registers (20 VGPR)
    const unsigned short* aHi = Whi + ((size_t)(2 * w) * KT) * 512 + (lane << 3);
    h16x8 aF[2][KT];
#pragma unroll
    for (int mt = 0; mt < 2; mt++)
#pragma unroll
        for (int kt = 0; kt < KT; kt++)
            aF[mt][kt] = *(const h16x8*)(aHi + ((mt * KT + kt) << 9));

    // readout/embed mapping: row = t>>4 (64 rows), rp = t&15 (16-way partials / 16 embed dims)
    const int rrow = t >> 4;
    const int rp   = t & 15;
    const int grow = row0 + rrow;

    // per-buffer base pointers (lane-derived, step-invariant)
    const int bofs = (lane & 15) * XS + ((lane >> 4) << 3);     // GEMM B-frag base (elems)
    const unsigned short* bp0 = xhh + bofs;
    const unsigned short* bp1 = xhh + XBUF + bofs;
    const float* orow = obs_l + rrow * 20;       // this thread's staged obs row

    float c8[2][4];
#pragma unroll
    for (int mt = 0; mt < 2; mt++)
#pragma unroll
        for (int nt = 0; nt < 4; nt++) c8[mt][nt] = 0.f;
    float pl0 = 0.f, pl1 = 0.f;                  // p_last (per-row, maintained by all 16 rp-threads)

    __syncthreads();

    // loop-invariant readout operands -> registers (same values, read once)
    const float4 w0a = *(const float4*)&wout[(rp << 3)];
    const float4 w0b = *(const float4*)&wout[(rp << 3) + 4];
    const float4 w1a = *(const float4*)&wout[HH + (rp << 3)];
    const float4 w1b = *(const float4*)&wout[HH + (rp << 3) + 4];
    const float we0 = wemb[2 * rp], we1 = wemb[2 * rp + 1], be = bemb[rp];

    // initial embed x[0] from obs delta into buffer 0: thread (rrow, rp=e)
    {
        float d0 = orow[2] - orow[0];
        float d1 = orow[3] - orow[1];
        float v = be + d0 * we0 + d1 * we1;
        v = v > 0.f ? v : 0.f;
        xhh[rrow * XS + rp] = f2h(v);
    }
    __syncthreads();

#pragma unroll 1
    for (int s = 0; s < NSTEP; s++) {
        const unsigned short* bhp  = (s & 1) ? bp1 : bp0;              // reads x(s)|h(s)
        unsigned short*       nxtb = xhh + ((s & 1) ? 0 : XBUF);       // receives h(s+1), x(s+1)

        // ---- gates GEMM: fully unrolled, immediate-offset ds_reads, register A ----
        f32x4 acc[2][4];
#pragma unroll
        for (int mt = 0; mt < 2; mt++)
#pragma unroll
            for (int nt = 0; nt < 4; nt++) acc[mt][nt] = bias[mt];

#pragma unroll
        for (int kt = 0; kt < KT; kt++) {
#pragma unroll
            for (int nt = 0; nt < 4; nt++) {
                h16x8 bH = *(const h16x8*)(bhp + kt * 32 + nt * 16 * XS);
                acc[0][nt] = __builtin_amdgcn_mfma_f32_16x16x32_f16(aF[0][kt], bH, acc[0][nt], 0, 0, 0);
                acc[1][nt] = __builtin_amdgcn_mfma_f32_16x16x32_f16(aF[1][kt], bH, acc[1][nt], 0, 0, 0);
            }
        }

        // ---- cell update + h-write straight to the OTHER buffer (no barrier needed) ----
#pragma unroll
        for (int mt = 0; mt < 2; mt++)
#pragma unroll
            for (int nt = 0; nt < 4; nt++) {
                f32x4 g = acc[mt][nt];
                float cn = sigm(g[1]) * c8[mt][nt] + sigm(g[0]) * ftanh(g[2]);
                c8[mt][nt] = cn;
                float hn = sigm(g[3]) * ftanh(cn);
                int row = nt * 16 + (lane & 15);
                int j   = 8 * w + mt * 4 + (lane >> 4);
                nxtb[row * XS + EE + j] = f2h(hn);
            }

        __syncthreads();   // B1: h(s+1) visible in nxtb

        // ---- readout + position + next-step embed (reads nxtb h; embed writes nxtb x) ----
        {
            const unsigned short* ph = &nxtb[rrow * XS + EE + (rp << 3)];
            s16x8 uh = *(const s16x8*)ph;
            float hv[8];
#pragma unroll
            for (int q = 0; q < 8; q++)
                hv[q] = h2f((unsigned short)uh[q]);
            float r0 = hv[0]*w0a.x + hv[1]*w0a.y + hv[2]*w0a.z + hv[3]*w0a.w
                     + hv[4]*w0b.x + hv[5]*w0b.y + hv[6]*w0b.z + hv[7]*w0b.w;
            float r1 = hv[0]*w1a.x + hv[1]*w1a.y + hv[2]*w1a.z + hv[3]*w1a.w
                     + hv[4]*w1b.x + hv[5]*w1b.y + hv[6]*w1b.z + hv[7]*w1b.w;
#pragma unroll
            for (int m = 1; m < 16; m <<= 1) {
                r0 += __shfl_xor(r0, m, 64);
                r1 += __shfl_xor(r1, m, 64);
            }
            float base0, base1;
            if (s < OBS) {
                base0 = orow[(s + 1) * 2 + 0];
                base1 = orow[(s + 1) * 2 + 1];
            } else {
                base0 = pl0; base1 = pl1;
            }
            float pos0 = base0 + r0 + bo0;
            float pos1 = base1 + r1 + bo1;
            if (rp == 0) {
                out[((size_t)s * BB + grow) * 2 + 0] = pos0;
                out[((size_t)s * BB + grow) * 2 + 1] = pos1;
            }
            if (s + 1 < NSTEP) {
                float d0, d1;
                if (s + 1 < OBS) {
                    d0 = orow[(s + 2) * 2 + 0] - orow[(s + 1) * 2 + 0];
                    d1 = orow[(s + 2) * 2 + 1] - orow[(s + 1) * 2 + 1];
                } else {
                    d0 = pos0 - pl0;            // p_last_new - p_prev_new
                    d1 = pos1 - pl1;
                }
                float v = be + d0 * we0 + d1 * we1;
                v = v > 0.f ? v : 0.f;
                nxtb[rrow * XS + rp] = f2h(v);  // x-region write; disjoint from h-reads above
            }
            pl0 = pos0; pl1 = pos1;
        }
        __syncthreads();   // B2: x(s+1)+h(s+1) consistent in nxtb before next GEMM
    }
}

extern "C" void kernel_launch(void* const* d_in, const int* in_sizes, int n_in,
                              void* d_out, int out_size, void* d_ws, size_t ws_size,
                              hipStream_t stream)
{
    const float* obs   = (const float*)d_in[0];
    const float* W_emb = (const float*)d_in[1];
    const float* b_emb = (const float*)d_in[2];
    const float* W_ih  = (const float*)d_in[3];
    const float* b_ih  = (const float*)d_in[4];
    const float* W_hh  = (const float*)d_in[5];
    const float* b_hh  = (const float*)d_in[6];
    const float* W_out = (const float*)d_in[7];
    const float* b_out = (const float*)d_in[8];
    float* out = (float*)d_out;

    unsigned short* Whi = (unsigned short*)d_ws;        // 32*5*64*8 = 81920 fp16

    hipLaunchKernelGGL(k_prep, dim3(32 * KT * 64 * 8 / 256), dim3(256), 0, stream,
                       W_ih, W_hh, Whi);

    hipLaunchKernelGGL(k_lstm, dim3(BB / MROWS), dim3(TPB), 0, stream,
                       obs, W_emb, b_emb, b_ih, b_hh, Whi, W_out, b_out, out);
}

// Round 16
// 228.567 us; speedup vs baseline: 1.0750x; 1.0750x over previous
//
#include <hip/hip_runtime.h>
#include <hip/hip_fp16.h>
#include <math.h>

#define BB 32768
#define EE 16
#define HH 128
#define KP 160          // padded K: 16 x + 128 h + 16 zeros
#define XS 168          // xh row stride (f16 elems): 168*2B=336B -> 16B-aligned, 8 bank-start spread
#define OBS 8
#define NSTEP 19
#define TPB 1024
#define MROWS 64        // batch rows per block (128 spills: R5/R13 -- twice-dead)
#define KT 5            // K-tiles of 32
#define XBUF (MROWS * XS)   // one xh buffer (f16 elems); two buffers double-buffered

typedef short s16x8 __attribute__((ext_vector_type(8)));     // raw 16-bit x8 (LDS storage view)
typedef _Float16 h16x8 __attribute__((ext_vector_type(8)));  // 8 fp16 (4 VGPRs), MFMA A/B frag
typedef float f32x4 __attribute__((ext_vector_type(4)));     // MFMA C/D frag

// Transcendentals via the NATIVE v_exp_f32 (2^x): R15 measured VALUBusy 57->51 from this.
#define NLOG2E  1.4426950408889634f
#define N2LOG2E 2.8853900817779268f
__device__ __forceinline__ float sigm(float x){
    return __builtin_amdgcn_rcpf(1.0f + __builtin_amdgcn_exp2f(-NLOG2E * x));
}
__device__ __forceinline__ float ftanh(float x){
    float e = __builtin_amdgcn_exp2f(-N2LOG2E * x);
    return (1.f - e) * __builtin_amdgcn_rcpf(1.f + e);
}
__device__ __forceinline__ unsigned short f2h(float x){
    __half h = __float2half(x);                 // RNE, single v_cvt_f16_f32
    return __half_as_ushort(h);
}
__device__ __forceinline__ float h2f(unsigned short u){ return __half2float(__ushort_as_half(u)); }

// Pack W_cat = [W_ih | W_hh] (K=144, zero-pad to 160) into MFMA A-operand fragment order,
// single fp16.  Frag (JT 0..31, kt 0..4): lane l, elem j holds
//   W_cat[k = kt*32 + (l>>4)*8 + j][jg = JT*16 + (l&15)],  jg = 4*j_hidden + gate.
__global__ __launch_bounds__(256) void k_prep(
    const float* __restrict__ W_ih, const float* __restrict__ W_hh,
    unsigned short* __restrict__ Whi)
{
    int idx = blockIdx.x * 256 + threadIdx.x;      // exactly 32*5*64*8 = 81920 threads
    int j    = idx & 7;
    int lane = (idx >> 3) & 63;
    int kt   = (idx >> 9) % KT;
    int JT   = idx / (KT * 512);
    int k  = kt * 32 + ((lane >> 4) << 3) + j;
    int jg = JT * 16 + (lane & 15);
    int col = (jg & 3) * HH + (jg >> 2);           // original gate row: g*128 + j_hidden
    float wv = 0.f;
    if (k < EE)            wv = W_ih[col * EE + k];
    else if (k < EE + HH)  wv = W_hh[col * HH + (k - EE)];
    Whi[idx] = f2h(wv);
}

// R15 minus the wout register hoist (it spilled: WRITE_SIZE 4.9->14.3MB, dur +7us).
// wout float4 reads are back INSIDE the step loop (R14 text, no spill at VGPR 60).
// Kept from R15: native exp2 transcendentals (VALUBusy 57->51), obs LDS staging
// (per-step global obs loads -> ds_reads), we/be scalar hoists.
__global__ __attribute__((amdgpu_flat_work_group_size(TPB, TPB)))
           __attribute__((amdgpu_waves_per_eu(4, 4)))
void k_lstm(
    const float* __restrict__ obs,
    const float* __restrict__ W_emb, const float* __restrict__ b_emb,
    const float* __restrict__ b_ih,  const float* __restrict__ b_hh,
    const unsigned short* __restrict__ Whi,
    const float* __restrict__ W_out, const float* __restrict__ b_out,
    float* __restrict__ out)
{
    __shared__ unsigned short xhh[2 * XBUF];     // fp16 of [x(16)|h(128)|0(16)|pad] x2 buffers
    __shared__ float wout[2 * HH];
    __shared__ float wemb[EE * 2];
    __shared__ float bemb[EE];
    __shared__ float obs_l[MROWS * 20];          // [row][frame 0..8][xy], stride 20 f32

    const int t    = threadIdx.x;
    const int lane = t & 63;
    const int w    = t >> 6;                     // wave 0..15: gate-cols jg in [w*32,(w+1)*32)
    const int row0 = blockIdx.x * MROWS;

    if (t < 2 * HH) wout[t] = W_out[t];          // rows 0,1 of W_out (contiguous)
    if (t < EE * 2) wemb[t] = W_emb[t];
    if (t < EE)     bemb[t] = b_emb[t];
    for (int i = t; i < 2 * XBUF; i += TPB) { xhh[i] = 0; }
    for (int i = t; i < MROWS * 18; i += TPB) {  // stage obs frames for this block's rows
        int row = i / 18, rem = i % 18, si = rem >> 1, xy = rem & 1;
        obs_l[row * 20 + (si << 1) + xy] = obs[(size_t)si * BB * 2 + (row0 + row) * 2 + xy];
    }

    // per-lane gate biases: acc[mt] reg r <-> jg = (2w+mt)*16 + (lane>>4)*4 + r
    f32x4 bias[2];
#pragma unroll
    for (int mt = 0; mt < 2; mt++)
#pragma unroll
        for (int r = 0; r < 4; r++) {
            int jg  = (2 * w + mt) * 16 + ((lane >> 4) << 2) + r;
            int col = (jg & 3) * HH + (jg >> 2);
            bias[mt][r] = b_ih[col] + b_hh[col];
        }
    const float bo0 = b_out[0], bo1 = b_out[1];

    // A-fragments: loop-invariant across all steps -> load ONCE into registers (20 VGPR)
    const unsigned short* aHi = Whi + ((size_t)(2 * w) * KT) * 512 + (lane << 3);
    h16x8 aF[2][KT];
#pragma unroll
    for (int mt = 0; mt < 2; mt++)
#pragma unroll
        for (int kt = 0; kt < KT; kt++)
            aF[mt][kt] = *(const h16x8*)(aHi + ((mt * KT + kt) << 9));

    // readout/embed mapping: row = t>>4 (64 rows), rp = t&15 (16-way partials / 16 embed dims)
    const int rrow = t >> 4;
    const int rp   = t & 15;
    const int grow = row0 + rrow;

    // per-buffer base pointers (lane-derived, step-invariant)
    const int bofs = (lane & 15) * XS + ((lane >> 4) << 3);     // GEMM B-frag base (elems)
    const unsigned short* bp0 = xhh + bofs;
    const unsigned short* bp1 = xhh + XBUF + bofs;
    const float* orow = obs_l + rrow * 20;       // this thread's staged obs row

    float c8[2][4];
#pragma unroll
    for (int mt = 0; mt < 2; mt++)
#pragma unroll
        for (int nt = 0; nt < 4; nt++) c8[mt][nt] = 0.f;
    float pl0 = 0.f, pl1 = 0.f;                  // p_last (per-row, maintained by all 16 rp-threads)

    __syncthreads();

    // embed scalar operands (3 regs -- cheap, no spill risk)
    const float we0 = wemb[2 * rp], we1 = wemb[2 * rp + 1], be = bemb[rp];

    // initial embed x[0] from obs delta into buffer 0: thread (rrow, rp=e)
    {
        float d0 = orow[2] - orow[0];
        float d1 = orow[3] - orow[1];
        float v = be + d0 * we0 + d1 * we1;
        v = v > 0.f ? v : 0.f;
        xhh[rrow * XS + rp] = f2h(v);
    }
    __syncthreads();

#pragma unroll 1
    for (int s = 0; s < NSTEP; s++) {
        const unsigned short* bhp  = (s & 1) ? bp1 : bp0;              // reads x(s)|h(s)
        unsigned short*       nxtb = xhh + ((s & 1) ? 0 : XBUF);       // receives h(s+1), x(s+1)

        // ---- gates GEMM: fully unrolled, immediate-offset ds_reads, register A ----
        f32x4 acc[2][4];
#pragma unroll
        for (int mt = 0; mt < 2; mt++)
#pragma unroll
            for (int nt = 0; nt < 4; nt++) acc[mt][nt] = bias[mt];

#pragma unroll
        for (int kt = 0; kt < KT; kt++) {
#pragma unroll
            for (int nt = 0; nt < 4; nt++) {
                h16x8 bH = *(const h16x8*)(bhp + kt * 32 + nt * 16 * XS);
                acc[0][nt] = __builtin_amdgcn_mfma_f32_16x16x32_f16(aF[0][kt], bH, acc[0][nt], 0, 0, 0);
                acc[1][nt] = __builtin_amdgcn_mfma_f32_16x16x32_f16(aF[1][kt], bH, acc[1][nt], 0, 0, 0);
            }
        }

        // ---- cell update + h-write straight to the OTHER buffer (no barrier needed) ----
#pragma unroll
        for (int mt = 0; mt < 2; mt++)
#pragma unroll
            for (int nt = 0; nt < 4; nt++) {
                f32x4 g = acc[mt][nt];
                float cn = sigm(g[1]) * c8[mt][nt] + sigm(g[0]) * ftanh(g[2]);
                c8[mt][nt] = cn;
                float hn = sigm(g[3]) * ftanh(cn);
                int row = nt * 16 + (lane & 15);
                int j   = 8 * w + mt * 4 + (lane >> 4);
                nxtb[row * XS + EE + j] = f2h(hn);
            }

        __syncthreads();   // B1: h(s+1) visible in nxtb

        // ---- readout + position + next-step embed (reads nxtb h; embed writes nxtb x) ----
        {
            const unsigned short* ph = &nxtb[rrow * XS + EE + (rp << 3)];
            s16x8 uh = *(const s16x8*)ph;
            float4 w0a = *(const float4*)&wout[(rp << 3)];
            float4 w0b = *(const float4*)&wout[(rp << 3) + 4];
            float4 w1a = *(const float4*)&wout[HH + (rp << 3)];
            float4 w1b = *(const float4*)&wout[HH + (rp << 3) + 4];
            float hv[8];
#pragma unroll
            for (int q = 0; q < 8; q++)
                hv[q] = h2f((unsigned short)uh[q]);
            float r0 = hv[0]*w0a.x + hv[1]*w0a.y + hv[2]*w0a.z + hv[3]*w0a.w
                     + hv[4]*w0b.x + hv[5]*w0b.y + hv[6]*w0b.z + hv[7]*w0b.w;
            float r1 = hv[0]*w1a.x + hv[1]*w1a.y + hv[2]*w1a.z + hv[3]*w1a.w
                     + hv[4]*w1b.x + hv[5]*w1b.y + hv[6]*w1b.z + hv[7]*w1b.w;
#pragma unroll
            for (int m = 1; m < 16; m <<= 1) {
                r0 += __shfl_xor(r0, m, 64);
                r1 += __shfl_xor(r1, m, 64);
            }
            float base0, base1;
            if (s < OBS) {
                base0 = orow[(s + 1) * 2 + 0];
                base1 = orow[(s + 1) * 2 + 1];
            } else {
                base0 = pl0; base1 = pl1;
            }
            float pos0 = base0 + r0 + bo0;
            float pos1 = base1 + r1 + bo1;
            if (rp == 0) {
                out[((size_t)s * BB + grow) * 2 + 0] = pos0;
                out[((size_t)s * BB + grow) * 2 + 1] = pos1;
            }
            if (s + 1 < NSTEP) {
                float d0, d1;
                if (s + 1 < OBS) {
                    d0 = orow[(s + 2) * 2 + 0] - orow[(s + 1) * 2 + 0];
                    d1 = orow[(s + 2) * 2 + 1] - orow[(s + 1) * 2 + 1];
                } else {
                    d0 = pos0 - pl0;            // p_last_new - p_prev_new
                    d1 = pos1 - pl1;
                }
                float v = be + d0 * we0 + d1 * we1;
                v = v > 0.f ? v : 0.f;
                nxtb[rrow * XS + rp] = f2h(v);  // x-region write; disjoint from h-reads above
            }
            pl0 = pos0; pl1 = pos1;
        }
        __syncthreads();   // B2: x(s+1)+h(s+1) consistent in nxtb before next GEMM
    }
}

extern "C" void kernel_launch(void* const* d_in, const int* in_sizes, int n_in,
                              void* d_out, int out_size, void* d_ws, size_t ws_size,
                              hipStream_t stream)
{
    const float* obs   = (const float*)d_in[0];
    const float* W_emb = (const float*)d_in[1];
    const float* b_emb = (const float*)d_in[2];
    const float* W_ih  = (const float*)d_in[3];
    const float* b_ih  = (const float*)d_in[4];
    const float* W_hh  = (const float*)d_in[5];
    const float* b_hh  = (const float*)d_in[6];
    const float* W_out = (const float*)d_in[7];
    const float* b_out = (const float*)d_in[8];
    float* out = (float*)d_out;

    unsigned short* Whi = (unsigned short*)d_ws;        // 32*5*64*8 = 81920 fp16

    hipLaunchKernelGGL(k_prep, dim3(32 * KT * 64 * 8 / 256), dim3(256), 0, stream,
                       W_ih, W_hh, Whi);

    hipLaunchKernelGGL(k_lstm, dim3(BB / MROWS), dim3(TPB), 0, stream,
                       obs, W_emb, b_emb, b_ih, b_hh, Whi, W_out, b_out, out);
}